// Round 8
// baseline (317.041 us; speedup 1.0000x reference)
//
#include <hip/hip_runtime.h>
#include <math.h>

// MinkowskiInstanceNorm: segment instance-norm, N x C=32, S<=64 segments (sorted seg_ids).
// ws (floats):
//   OVF_SUM[2048]@0, OVF_SQ[2048]@2048, OVF_CNT[64]@4096   (boundary-block atomics)
//   SCALE[2048]@4160, SHIFT[2048]@6208
//   PART@8256: per-block records, 68 floats each: sum[32], sq[32], cnt, segid, pad[2]

#define WS_OVF     0
#define WS_OVF_CNT 4096
#define WS_SCALE   4160
#define WS_SHIFT   6208
#define WS_PART    8256
#define PART_STRIDE 68   // floats (=17 float4, 16B-aligned)

typedef float f32x4 __attribute__((ext_vector_type(4)));

__global__ void zero_ws_kernel(float* __restrict__ ws) {
    int t = blockIdx.x * blockDim.x + threadIdx.x;
    if (t < 4160) ws[t] = 0.0f;   // overflow bins + cnt
}

// Block owns 4096 consecutive float4 (=512 rows). Thread t: i = blk*4096 + k*256 + t,
// k=0..15. cg = t&7 = channel-group of every element this thread touches.
__global__ __launch_bounds__(256) void reduce_kernel(
        const f32x4* __restrict__ f4, const int* __restrict__ seg,
        float* __restrict__ ws, int total4, int N) {
    __shared__ __align__(16) float smem[4224];
    f32x4* s_sum = (f32x4*)smem;            // 256 f32x4
    f32x4* s_sq  = (f32x4*)(smem + 1024);   // 256 f32x4

    int t   = threadIdx.x;
    int cg  = t & 7;
    int blk = blockIdx.x;
    int base = blk * 4096;
    bool full = (base + 4096) <= total4;
    int row_first = base >> 3;
    int row_last  = min((base + 4095) >> 3, N - 1);
    int sA = seg[row_first];
    int sB = seg[row_last];
    float* part = ws + WS_PART + blk * PART_STRIDE;

    if (full && sA == sB) {
        // ---- fast path: 2 x 8 independent loads, 4 accumulator pairs ----
        f32x4 a0 = {0.f,0.f,0.f,0.f}, a1 = a0, a2 = a0, a3 = a0;
        f32x4 q0 = a0, q1 = a0, q2 = a0, q3 = a0;
        const f32x4* p = f4 + base + t;
        for (int it = 0; it < 2; ++it) {
            f32x4 v0 = p[0 * 256];
            f32x4 v1 = p[1 * 256];
            f32x4 v2 = p[2 * 256];
            f32x4 v3 = p[3 * 256];
            f32x4 v4 = p[4 * 256];
            f32x4 v5 = p[5 * 256];
            f32x4 v6 = p[6 * 256];
            f32x4 v7 = p[7 * 256];
            a0 += v0; q0 += v0 * v0;
            a1 += v1; q1 += v1 * v1;
            a2 += v2; q2 += v2 * v2;
            a3 += v3; q3 += v3 * v3;
            a0 += v4; q0 += v4 * v4;
            a1 += v5; q1 += v5 * v5;
            a2 += v6; q2 += v6 * v6;
            a3 += v7; q3 += v7 * v7;
            p += 2048;
        }
        a0 = (a0 + a1) + (a2 + a3);
        q0 = (q0 + q1) + (q2 + q3);
        s_sum[t] = a0;
        s_sq[t]  = q0;
        __syncthreads();
        for (int off = 128; off >= 8; off >>= 1) {
            if (t < off) {
                s_sum[t] += s_sum[t + off];
                s_sq[t]  += s_sq[t + off];
            }
            __syncthreads();
        }
        // record: threads 0..7 hold channel-group totals (t == cg)
        f32x4* pr = (f32x4*)part;
        if (t < 8) {
            pr[t]     = s_sum[t];
            pr[8 + t] = s_sq[t];
        }
        if (t == 0) {
            f32x4 meta = {512.0f, (float)sA, 0.f, 0.f};
            pr[16] = meta;
        }
    } else {
        // ---- boundary/tail path (<=8 blocks): LDS bins -> overflow atomics ----
        for (int j = t; j < 4160; j += 256) smem[j] = 0.0f;
        __syncthreads();
        for (int k = 0; k < 16; ++k) {
            int i = base + k * 256 + t;
            if (i < total4) {
                int s = seg[i >> 3];
                f32x4 v = f4[i];
                int bse = s * 32 + cg * 4;
                atomicAdd(&smem[bse + 0], v.x);
                atomicAdd(&smem[bse + 1], v.y);
                atomicAdd(&smem[bse + 2], v.z);
                atomicAdd(&smem[bse + 3], v.w);
                atomicAdd(&smem[2048 + bse + 0], v.x * v.x);
                atomicAdd(&smem[2048 + bse + 1], v.y * v.y);
                atomicAdd(&smem[2048 + bse + 2], v.z * v.z);
                atomicAdd(&smem[2048 + bse + 3], v.w * v.w);
                if (cg == 0) atomicAdd(&smem[4096 + s], 1.0f);
            }
        }
        __syncthreads();
        for (int j = t; j < 4160; j += 256) {
            float v = smem[j];
            if (v != 0.0f) atomicAdd(&ws[WS_OVF + j], v);
        }
        if (t == 0) {
            f32x4 meta = {0.0f, -1.0f, 0.f, 0.f};   // invalid record
            ((f32x4*)part)[16] = meta;
        }
    }
}

// 64 blocks; block s sums partial records + overflow for segment s, writes scale/shift.
__global__ __launch_bounds__(256) void finalize_kernel(
        const float* __restrict__ w, const float* __restrict__ b,
        const int* __restrict__ nsp, float* __restrict__ ws, int nblk) {
    __shared__ float L1[8][32];
    __shared__ float L2[8][32];
    __shared__ float L3[8];
    int s = blockIdx.x;
    int ns = min(*nsp, 64);
    if (s >= ns) return;

    int t = threadIdx.x;
    int c = t & 31;
    int g = t >> 5;                       // 8 groups of 32
    const float* part = ws + WS_PART;

    float asum = 0.f, asq = 0.f, acnt = 0.f;
    for (int rec = g; rec < nblk; rec += 8) {
        const float* R = part + rec * PART_STRIDE;
        if (R[65] == (float)s) {
            asum += R[c];
            asq  += R[32 + c];
            if (c == 0) acnt += R[64];
        }
    }
    L1[g][c] = asum;
    L2[g][c] = asq;
    if (c == 0) L3[g] = acnt;
    __syncthreads();
    if (g == 0) {
        float S = 0.f, Q = 0.f, C2 = 0.f;
        #pragma unroll
        for (int j = 0; j < 8; ++j) { S += L1[j][c]; Q += L2[j][c]; C2 += L3[j]; }
        S  += ws[WS_OVF + s * 32 + c];
        Q  += ws[WS_OVF + 2048 + s * 32 + c];
        C2 += ws[WS_OVF_CNT + s];
        float cnt  = fmaxf(C2, 1.0f);
        float mean = S / cnt;
        float var  = fmaxf(Q / cnt - mean * mean, 0.0f);
        float inv  = rsqrtf(var + 1e-8f);
        float sc   = inv * w[c];
        ws[WS_SCALE + s * 32 + c] = sc;
        ws[WS_SHIFT + s * 32 + c] = b[c] - mean * sc;
    }
}

__global__ __launch_bounds__(256) void apply_kernel(
        const float* __restrict__ feats, const int* __restrict__ seg,
        const float* __restrict__ ws, float* __restrict__ out, int total4) {
    const f32x4* f4 = (const f32x4*)feats;
    f32x4*       o4 = (f32x4*)out;
    const f32x4* scale4 = (const f32x4*)(ws + WS_SCALE);
    const f32x4* shift4 = (const f32x4*)(ws + WS_SHIFT);
    int stride = gridDim.x * blockDim.x;
    for (int i = blockIdx.x * blockDim.x + threadIdx.x; i < total4; i += stride) {
        int row = i >> 3, cg = i & 7;
        int s = seg[row];
        f32x4 v  = __builtin_nontemporal_load(&f4[i]);
        f32x4 sc = scale4[s * 8 + cg];
        f32x4 sh = shift4[s * 8 + cg];
        f32x4 o;
        o.x = fmaf(v.x, sc.x, sh.x); o.y = fmaf(v.y, sc.y, sh.y);
        o.z = fmaf(v.z, sc.z, sh.z); o.w = fmaf(v.w, sc.w, sh.w);
        __builtin_nontemporal_store(o, &o4[i]);
    }
}

extern "C" void kernel_launch(void* const* d_in, const int* in_sizes, int n_in,
                              void* d_out, int out_size, void* d_ws, size_t ws_size,
                              hipStream_t stream) {
    const float* feats = (const float*)d_in[0];
    const int*   seg   = (const int*)d_in[1];
    const float* w     = (const float*)d_in[2];
    const float* b     = (const float*)d_in[3];
    const int*   nsp   = (const int*)d_in[4];
    float* out = (float*)d_out;
    float* ws  = (float*)d_ws;

    int N = in_sizes[1];
    int total4 = N * 8;
    int nblk = (total4 + 4095) / 4096;

    hipLaunchKernelGGL(zero_ws_kernel, dim3(17), dim3(256), 0, stream, ws);
    hipLaunchKernelGGL(reduce_kernel, dim3(nblk), dim3(256), 0, stream,
                       (const f32x4*)feats, seg, ws, total4, N);
    hipLaunchKernelGGL(finalize_kernel, dim3(64), dim3(256), 0, stream,
                       w, b, nsp, ws, nblk);
    hipLaunchKernelGGL(apply_kernel, dim3(4096), dim3(256), 0, stream,
                       feats, seg, ws, out, total4);
}